// Round 8
// baseline (5379.617 us; speedup 1.0000x reference)
//
#include <hip/hip_runtime.h>

// Residual 2-layer LSTM, T=256 B=64 H=1024, fp32 io, bf16 MFMA compute.
//
// R11 = R10 (2836us: fused persistent kernel, XCD-partitioned roles, bf16
// blocked x via cvt prologue, aliased buf with deferred out5 publish) +
// WG CONSOLIDATION 128->64 WGs per layer (16 h-cols per WG, 128 WGs total):
//
//  - Each WG now owns 16 h-cols (64 gate-cols). Weight frags double to
//    wfx[32]+wfh[32] = 256 VGPRs/lane (free: 1 wave/SIMD either way, total
//    ~360 < 512, no spill). MFMAs per phase double (8kk x 4m x 4n = 128)
//    while the per-WG A-tile reads are UNCHANGED (same full 64x1024 tile).
//  - Sync participants halve: 64 flags/array/step, ONE 64-lane poll load
//    covers all producers; straggler set 128 -> 64; poller count halves.
//  - L2 amplification halves: 16 WGs/XCD x 256KB = 4MB/XCD/step (was 8MB).
//  - Only 128 of 256 CUs active -> DPM power headroom (possible clock bump).
//
// Preserved shape-for-shape (proven load-bearing by R5-R8): publish window
// (h store -> vmcnt(0) -> barrier -> flag) then tail (deferred out5[t-1]
// store -> drain -> barrier -> flagO), wave0-only polling with s_sleep(2)
// + release barrier, XCD partition (L5 = XCDs 0-3, L6 = XCDs 4-7).
// Math is bit-identical: same K-split per wave, same kk and cross-wave
// summation order, same f2bf rounding everywhere.
//
// Coherence (one dispatch, no boundary flush): out5/h5/h6 written with
// AGENT-scope 4B stores + vmcnt(0) drain before their flag. Reader-side
// cached loads are safe per the virgin-address argument + XCD partition
// (only XCDs 0-3 ever cache pristine xb lines; L6 readers on XCDs 4-7
// pull post-overwrite lines fresh from LLC).

#define TT 256
#define BB 64
#define HH 1024
#define CB 64   // column blocks per layer (16 h-cols each)
#define BH (BB * HH)

typedef __attribute__((ext_vector_type(8))) short short8;
typedef __attribute__((ext_vector_type(4))) float float4v;
typedef __attribute__((ext_vector_type(2))) float float2v;

__device__ __forceinline__ unsigned short f2bf(float f) {
  unsigned u = __builtin_bit_cast(unsigned, f);
  u += 0x7fffu + ((u >> 16) & 1u);
  return (unsigned short)(u >> 16);
}
__device__ __forceinline__ float bf2f(unsigned short s) {
  unsigned u = ((unsigned)s) << 16;
  return __builtin_bit_cast(float, u);
}
__device__ __forceinline__ float fexp2(float x) { return __builtin_amdgcn_exp2f(x); }
__device__ __forceinline__ float frcp(float x) { return __builtin_amdgcn_rcpf(x); }
__device__ __forceinline__ float sigm(float x) {
  return frcp(1.0f + fexp2(-1.4426950408889634f * x));
}
__device__ __forceinline__ float tanha(float x) {
  return 1.0f - 2.0f * frcp(1.0f + fexp2(2.8853900817779268f * x));
}

// x fp32 [t][b][h] -> bf16 blocked [t][h>>3][b][h&7]. Same f2bf rounding as
// the on-the-fly cvt -> bit-identical numerics.
__global__ __launch_bounds__(256) void cvt_x_blocked(const float* __restrict__ in,
                                                     unsigned short* __restrict__ out) {
  const int i = blockIdx.x * 256 + threadIdx.x; // [0, TT*BB*HH/8)
  const int t = i >> 13;
  const int r = i & 8191;
  const int c = r >> 6;  // h>>3
  const int b = r & 63;
  const float* src = in + ((size_t)t << 16) + b * 1024 + (c << 3);
  const float4v a = *(const float4v*)src;
  const float4v d = *(const float4v*)(src + 4);
  short8 v;
  v[0] = (short)f2bf(a[0]); v[1] = (short)f2bf(a[1]);
  v[2] = (short)f2bf(a[2]); v[3] = (short)f2bf(a[3]);
  v[4] = (short)f2bf(d[0]); v[5] = (short)f2bf(d[1]);
  v[6] = (short)f2bf(d[2]); v[7] = (short)f2bf(d[3]);
  *(short8*)(out + ((size_t)t << 16) + c * 512 + b * 8) = v;
}

__global__ __launch_bounds__(256, 1) void lstm2_fused(
    const float* __restrict__ x,
    const float* __restrict__ wih5, const float* __restrict__ whh5,
    const float* __restrict__ bih5, const float* __restrict__ bhh5,
    const float* __restrict__ wih6, const float* __restrict__ whh6,
    const float* __restrict__ bih6, const float* __restrict__ bhh6,
    unsigned short* __restrict__ buf, unsigned short* __restrict__ hbuf5,
    unsigned short* __restrict__ hbuf6, float* __restrict__ out,
    int* __restrict__ flags5, int* __restrict__ flagsO,
    int* __restrict__ flags6) {
  // XCD partition: grid=128, round-robin placement -> xcd = bid & 7.
  // L5 -> XCDs 0-3, L6 -> XCDs 4-7; p enumerates [0,64) within each role.
  const int xcd = (int)(blockIdx.x & 7);
  const int role = (xcd >= 4) ? 1 : 0;            // 0 = layer5, 1 = layer6
  const int p = (int)(blockIdx.x >> 3) * 4 + (xcd & 3); // column block (16 h-cols)
  const int tid = threadIdx.x;
  const int w = tid >> 6;
  const int lane = tid & 63;
  const int ln = lane & 15;
  const int q = lane >> 4;

  __shared__ float gp[4][BB][67]; // 64 gate-cols + pad

  const float* wih = role ? wih6 : wih5;
  const float* whh = role ? whh6 : whh5;
  const float* bih = role ? bih6 : bih5;
  const float* bhh = role ? bhh6 : bhh5;
  unsigned short* hbuf = role ? hbuf6 : hbuf5;
  int* hflags = role ? flags6 : flags5;

  // ---- persistent weight fragments: this wave covers k in [256w, 256w+256)
  // wf[kk*4+nt]: gate = nt, h-col = p*16+ln, k = 256*w + kk*32 + 8*q + j
  short8 wfx[32], wfh[32];
#pragma unroll
  for (int kk = 0; kk < 8; ++kk) {
#pragma unroll
    for (int nt = 0; nt < 4; ++nt) {
      const int gidx = nt * HH + p * 16 + ln; // gate order i,f,g,o
      const int k0 = 256 * w + kk * 32 + 8 * q;
      const float* sx = wih + (size_t)gidx * HH + k0;
      const float* sh = whh + (size_t)gidx * HH + k0;
      short8 vx, vh;
#pragma unroll
      for (int j = 0; j < 8; ++j) { vx[j] = (short)f2bf(sx[j]); vh[j] = (short)f2bf(sh[j]); }
      wfx[kk * 4 + nt] = vx;
      wfh[kk * 4 + nt] = vh;
    }
  }

  // ---- elementwise state: thread owns (b=lane, h-cols 4w .. 4w+3)
  const int eb = lane;
  float bsum[4][4];
#pragma unroll
  for (int s = 0; s < 4; ++s) {
    const int jj = 4 * w + s;
#pragma unroll
    for (int gt = 0; gt < 4; ++gt) {
      const int gidx = gt * HH + p * 16 + jj;
      bsum[s][gt] = bih[gidx] + bhh[gidx];
    }
  }
  float cst[4] = {0.f, 0.f, 0.f, 0.f};
  unsigned po_prev0 = 0, po_prev1 = 0; // L5: packed out5 of PREVIOUS step

  // ---- A-operand offsets (blocked bf16 [t][col>>3][b][col&7]):
  // af row b = 16*mt + ln, k = 256*w + kk*32 + 8*q + j
  size_t rh[4];
#pragma unroll
  for (int mt = 0; mt < 4; ++mt)
    rh[mt] = (size_t)(16 * mt + ln) * 8 + (size_t)(256 * w + 8 * q) * 64;

  // h-publish address pieces: cols 4w+s -> col>>3 = p*2 + (w>>1),
  // col&7 = 4*(w&1)+s (s=0..3 contiguous)
  const size_t hoff = (size_t)(p * 2 + (w >> 1)) * 512 + (size_t)eb * 8 + 4 * (w & 1);

  for (int t = 0; t < TT; ++t) {
    float4v acc[4][4];
#pragma unroll
    for (int mt = 0; mt < 4; ++mt)
#pragma unroll
      for (int nt = 0; nt < 4; ++nt)
        acc[mt][nt] = (float4v){0.f, 0.f, 0.f, 0.f};

    if (role == 0) {
      // ---- layer5 x-part: blocked bf16 x from buf (slot t pristine until
      // step t+1's tail overwrites it with out5[t])
      const unsigned short* Ab = buf + (size_t)t * BH;
#pragma unroll
      for (int kk = 0; kk < 8; ++kk) {
        short8 af[4];
#pragma unroll
        for (int mt = 0; mt < 4; ++mt)
          af[mt] = *(const short8*)(Ab + rh[mt] + (size_t)kk * 2048);
#pragma unroll
        for (int mt = 0; mt < 4; ++mt)
#pragma unroll
          for (int nt = 0; nt < 4; ++nt)
            acc[mt][nt] = __builtin_amdgcn_mfma_f32_16x16x32_bf16(af[mt], wfx[kk * 4 + nt], acc[mt][nt], 0, 0, 0);
      }
      // gate h-part on all 64 layer-5 WGs having published h5[t-1]
      if (t > 0) {
        if (w == 0) {
          int* fl = flags5 + (size_t)(t - 1) * CB;
          for (;;) {
            const int a0 = __hip_atomic_load(fl + lane, __ATOMIC_RELAXED, __HIP_MEMORY_SCOPE_AGENT);
            if (__all(a0 != 0)) break;
            __builtin_amdgcn_s_sleep(2);
          }
        }
        __builtin_amdgcn_fence(__ATOMIC_ACQUIRE, "workgroup"); // compiler order only
        __syncthreads();
      }
    } else {
      // ---- layer6 gate: out5[t] ready (all 64) AND own h6[t-1] ready
      if (w == 0) {
        int* fo = flagsO + (size_t)t * CB;
        int* fh = flags6 + (size_t)(t > 0 ? t - 1 : 0) * CB;
        for (;;) {
          const int a0 = __hip_atomic_load(fo + lane, __ATOMIC_RELAXED, __HIP_MEMORY_SCOPE_AGENT);
          int ok = (a0 != 0);
          if (t > 0) {
            const int b0 = __hip_atomic_load(fh + lane, __ATOMIC_RELAXED, __HIP_MEMORY_SCOPE_AGENT);
            ok &= (b0 != 0);
          }
          if (__all(ok)) break;
          __builtin_amdgcn_s_sleep(2);
        }
      }
      __builtin_amdgcn_fence(__ATOMIC_ACQUIRE, "workgroup"); // compiler order only
      __syncthreads();
      // ---- layer6 x-part: out5 blocked bf16 from buf (cached; XCDs 4-7
      // never held these lines pre-write -> LLC-fresh)
      const unsigned short* Ab = buf + (size_t)t * BH;
#pragma unroll
      for (int kk = 0; kk < 8; ++kk) {
        short8 af[4];
#pragma unroll
        for (int mt = 0; mt < 4; ++mt)
          af[mt] = *(const short8*)(Ab + rh[mt] + (size_t)kk * 2048);
#pragma unroll
        for (int mt = 0; mt < 4; ++mt)
#pragma unroll
          for (int nt = 0; nt < 4; ++nt)
            acc[mt][nt] = __builtin_amdgcn_mfma_f32_16x16x32_bf16(af[mt], wfx[kk * 4 + nt], acc[mt][nt], 0, 0, 0);
      }
    }

    // ---- h-part (common; gating already done per-role above)
    if (t > 0) {
      const unsigned short* Hb = hbuf + (size_t)(t - 1) * BH;
#pragma unroll
      for (int kk = 0; kk < 8; ++kk) {
        short8 af[4];
#pragma unroll
        for (int mt = 0; mt < 4; ++mt)
          af[mt] = *(const short8*)(Hb + rh[mt] + (size_t)kk * 2048); // cached
#pragma unroll
        for (int mt = 0; mt < 4; ++mt)
#pragma unroll
          for (int nt = 0; nt < 4; ++nt)
            acc[mt][nt] = __builtin_amdgcn_mfma_f32_16x16x32_bf16(af[mt], wfh[kk * 4 + nt], acc[mt][nt], 0, 0, 0);
      }
    }

    // C layout: row m = 16*mt + 4*q + r, col n = 16*nt + ln
#pragma unroll
    for (int mt = 0; mt < 4; ++mt)
#pragma unroll
      for (int nt = 0; nt < 4; ++nt)
#pragma unroll
        for (int r = 0; r < 4; ++r)
          gp[w][16 * mt + 4 * q + r][16 * nt + ln] = acc[mt][nt][r];

    __syncthreads();

    const size_t tb = (size_t)t * BH;
    const size_t hidx = tb + hoff;
    float hv[4];
#pragma unroll
    for (int s = 0; s < 4; ++s) {
      const int jj = 4 * w + s;
      float iv = bsum[s][0], fv = bsum[s][1], gv = bsum[s][2], ov = bsum[s][3];
#pragma unroll
      for (int ww = 0; ww < 4; ++ww) {
        iv += gp[ww][eb][jj];
        fv += gp[ww][eb][16 + jj];
        gv += gp[ww][eb][32 + jj];
        ov += gp[ww][eb][48 + jj];
      }
      const float ig = sigm(iv);
      const float fg = sigm(fv);
      const float gg_ = tanha(gv);
      const float og = sigm(ov);
      const float c = fg * cst[s] + ig * gg_;
      cst[s] = c;
      hv[s] = og * tanha(c);
    }
    // publish h first: two packed 2xbf16 agent-scope 4B stores -> LLC
    {
      const unsigned u0 = (unsigned)f2bf(hv[0]) | ((unsigned)f2bf(hv[1]) << 16);
      const unsigned u1 = (unsigned)f2bf(hv[2]) | ((unsigned)f2bf(hv[3]) << 16);
      __hip_atomic_store((unsigned*)(hbuf + hidx), u0, __ATOMIC_RELAXED,
                         __HIP_MEMORY_SCOPE_AGENT);
      __hip_atomic_store((unsigned*)(hbuf + hidx + 2), u1, __ATOMIC_RELAXED,
                         __HIP_MEMORY_SCOPE_AGENT);
    }
    asm volatile("s_waitcnt vmcnt(0)" ::: "memory"); // h stores at coherent point
    __syncthreads();
    if (tid == 0)
      __hip_atomic_store(hflags + (size_t)t * CB + p, 1, __ATOMIC_RELAXED,
                         __HIP_MEMORY_SCOPE_AGENT);

    // ---- output tail (phase-separation: keeps the local WG's fabric quiet
    // window while remote pollers' critical h-loads complete)
    if (role == 0) {
      if (t > 0) {
        // deferred publish: out5[t-1] into buf slot t-1 (safe -- this step's
        // h-gate confirmed all flags5[t-1], so every L5 WG finished reading
        // slot t-1 as x)
        __hip_atomic_store((unsigned*)(buf + (hidx - BH)), po_prev0, __ATOMIC_RELAXED,
                           __HIP_MEMORY_SCOPE_AGENT);
        __hip_atomic_store((unsigned*)(buf + (hidx - BH) + 2), po_prev1, __ATOMIC_RELAXED,
                           __HIP_MEMORY_SCOPE_AGENT);
        asm volatile("s_waitcnt vmcnt(0)" ::: "memory");
        __syncthreads();
        if (tid == 0)
          __hip_atomic_store(flagsO + (size_t)(t - 1) * CB + p, 1, __ATOMIC_RELAXED,
                             __HIP_MEMORY_SCOPE_AGENT);
      }
      // prepare next step's deferred value: out5[t] = h5[t] + x residual
      const float4v r = *(const float4v*)(x + tb + (size_t)eb * HH + p * 16 + 4 * w);
      po_prev0 = (unsigned)f2bf(hv[0] + r[0]) | ((unsigned)f2bf(hv[1] + r[1]) << 16);
      po_prev1 = (unsigned)f2bf(hv[2] + r[2]) | ((unsigned)f2bf(hv[3] + r[3]) << 16);
    } else {
      // final out = h6 + out5 residual (cached read of own cols; published
      // under flagsO[t] which this WG confirmed before its x-part)
      const unsigned rb0 = *(const unsigned*)(buf + hidx);
      const unsigned rb1 = *(const unsigned*)(buf + hidx + 2);
      float4v vo;
      vo[0] = hv[0] + bf2f((unsigned short)(rb0 & 0xffff));
      vo[1] = hv[1] + bf2f((unsigned short)(rb0 >> 16));
      vo[2] = hv[2] + bf2f((unsigned short)(rb1 & 0xffff));
      vo[3] = hv[3] + bf2f((unsigned short)(rb1 >> 16));
      *(float4v*)(out + tb + (size_t)eb * HH + p * 16 + 4 * w) = vo;
    }
  }

  // ---- L5 epilogue: publish out5[TT-1] once all flags5[TT-1] are set
  if (role == 0) {
    if (w == 0) {
      int* fl = flags5 + (size_t)(TT - 1) * CB;
      for (;;) {
        const int a0 = __hip_atomic_load(fl + lane, __ATOMIC_RELAXED, __HIP_MEMORY_SCOPE_AGENT);
        if (__all(a0 != 0)) break;
        __builtin_amdgcn_s_sleep(2);
      }
    }
    __builtin_amdgcn_fence(__ATOMIC_ACQUIRE, "workgroup");
    __syncthreads();
    const size_t hlast = (size_t)(TT - 1) * BH + hoff;
    __hip_atomic_store((unsigned*)(buf + hlast), po_prev0, __ATOMIC_RELAXED,
                       __HIP_MEMORY_SCOPE_AGENT);
    __hip_atomic_store((unsigned*)(buf + hlast + 2), po_prev1, __ATOMIC_RELAXED,
                       __HIP_MEMORY_SCOPE_AGENT);
    asm volatile("s_waitcnt vmcnt(0)" ::: "memory");
    __syncthreads();
    if (tid == 0)
      __hip_atomic_store(flagsO + (size_t)(TT - 1) * CB + p, 1, __ATOMIC_RELAXED,
                         __HIP_MEMORY_SCOPE_AGENT);
  }
}

extern "C" void kernel_launch(void* const* d_in, const int* in_sizes, int n_in,
                              void* d_out, int out_size, void* d_ws, size_t ws_size,
                              hipStream_t stream) {
  const float* x    = (const float*)d_in[0];
  const float* wih5 = (const float*)d_in[1];
  const float* whh5 = (const float*)d_in[2];
  const float* bih5 = (const float*)d_in[3];
  const float* bhh5 = (const float*)d_in[4];
  const float* wih6 = (const float*)d_in[5];
  const float* whh6 = (const float*)d_in[6];
  const float* bih6 = (const float*)d_in[7];
  const float* bhh6 = (const float*)d_in[8];
  float* out = (float*)d_out;

  // ws (96.3 MB):
  //   [0,32M)   buf   : x bf16 blocked, ALIASED with layer5 output (out5);
  //                     slot t flips xb->out5 at L5 step t+1 (proven-dead)
  //   [32M,64M) hbuf5 : layer5 h history bf16 blocked
  //   [64M,96M) hbuf6 : layer6 h history bf16 blocked
  //   [96M,+192K) flags5 | flagsO | flags6 (TT*CB ints each)
  char* ws = (char*)d_ws;
  unsigned short* buf   = (unsigned short*)(ws);
  unsigned short* hbuf5 = (unsigned short*)(ws + 33554432);
  unsigned short* hbuf6 = (unsigned short*)(ws + 67108864);
  int* flags            = (int*)(ws + 100663296);
  int* flags5 = flags;
  int* flagsO = flags + TT * CB;
  int* flags6 = flags + 2 * TT * CB;

  hipMemsetAsync(flags, 0, 3 * TT * CB * sizeof(int), stream);

  cvt_x_blocked<<<dim3(TT * BB * HH / 8 / 256), dim3(256), 0, stream>>>(x, buf);

  lstm2_fused<<<dim3(2 * CB), dim3(256), 0, stream>>>(
      x, wih5, whh5, bih5, bhh5, wih6, whh6, bih6, bhh6,
      buf, hbuf5, hbuf6, out, flags5, flagsO, flags6);
}